// Round 10
// baseline (559.787 us; speedup 1.0000x reference)
//
#include <hip/hip_runtime.h>
#include <math.h>

#define D_   16
#define H_   56
#define W_   56
#define CIN  32
#define COUT 64
#define KPTS 27
#define NCH  81                  // 3*KPTS offset channels
#define NP   (D_*H_*W_)          // 50176 output positions
#define CHW  (D_*H_*W_)          // per-channel plane size
#define KPAD 28                  // 27 deform points padded to f4 multiple

typedef float f4 __attribute__((ext_vector_type(4)));

static __device__ __forceinline__ int iclamp(int v, int lo, int hi) {
    return v < lo ? lo : (v > hi ? hi : v);
}

// ---------------------------------------------------------------------------
// Prep 1: weight transposes.
//   weight [COUT][CIN][27taps]      -> wT  [tap][c][o]          (o contiguous)
//   offw   [81ch][CIN][27taps]      -> owT [tap][d][c][28]      (kpt contiguous,
//     ch = kpt*3 + d; slot 27 zero-padded)
// ---------------------------------------------------------------------------
__global__ __launch_bounds__(256) void k_prep(const float* __restrict__ w,
                                              const float* __restrict__ ow,
                                              float* __restrict__ wT,
                                              float* __restrict__ owT) {
    int i = blockIdx.x * 256 + threadIdx.x;
    if (i < COUT * CIN * KPTS) {
        int tap = i % KPTS;
        int c   = (i / KPTS) % CIN;
        int o   = i / (KPTS * CIN);
        wT[(tap * CIN + c) * COUT + o] = w[i];
    }
    if (i < NCH * CIN * KPTS) {
        int tap = i % KPTS;
        int c   = (i / KPTS) % CIN;
        int ch  = i / (KPTS * CIN);
        int d   = ch % 3;
        int kpt = ch / 3;
        owT[(((tap * 3) + d) * CIN + c) * KPAD + kpt] = ow[i];
    }
    if (i < KPTS * 3 * CIN)                      // zero the pad slot
        owT[i * KPAD + 27] = 0.0f;
}

// ---------------------------------------------------------------------------
// Prep 2: x [c][z][y][x] -> xT [z][y][x][c]  (channels-last, 6.4 MB)
// ---------------------------------------------------------------------------
__global__ __launch_bounds__(64) void k_xT(const float* __restrict__ x,
                                           float* __restrict__ xT) {
    const int s = blockIdx.x * 64 + threadIdx.x;
    float r[CIN];
#pragma unroll
    for (int c = 0; c < CIN; ++c) r[c] = x[c * CHW + s];
    f4* dst = (f4*)(xT + (size_t)s * CIN);
#pragma unroll
    for (int cc = 0; cc < 8; ++cc) {
        f4 v;
        v.x = r[cc * 4 + 0]; v.y = r[cc * 4 + 1];
        v.z = r[cc * 4 + 2]; v.w = r[cc * 4 + 3];
        dst[cc] = v;
    }
}

// ---------------------------------------------------------------------------
// Prep 3: out[o][p] = bias[o]  (k_dconv accumulates into it atomically)
// ---------------------------------------------------------------------------
__global__ __launch_bounds__(256) void k_init(const float* __restrict__ bias,
                                              float* __restrict__ out) {
    const int i   = blockIdx.x * 256 + threadIdx.x;  // float4 index
    const float b = bias[(i * 4) / NP];              // NP % 4 == 0
    f4 v; v.x = b; v.y = b; v.z = b; v.w = b;
    ((f4*)out)[i] = v;
}

// ---------------------------------------------------------------------------
// Kernel A: dense 3x3x3 conv -> offset channels, fused base-grid add.
// blockIdx.y = d. 27(+1 pad) accumulators in NAMED f4 registers A0..A6.
// Weights read DIRECTLY from the uniform global pointer: address depends only
// on kernel args + uniform loop vars -> compiler scalarizes to s_load (SMEM
// pipe), freeing the LDS unit entirely. No LDS, no barriers.
// ---------------------------------------------------------------------------
__global__ __launch_bounds__(64, 2) void k_offsets(const float* __restrict__ xT,
                                                   const float* __restrict__ owT,
                                                   const float* __restrict__ offb,
                                                   float* __restrict__ coords) {
    const int tid = threadIdx.x;
    const int p   = blockIdx.x * 64 + tid;
    const int d   = blockIdx.y;                      // uniform per block
    const int ox  = p % W_;
    const int t   = p / W_;
    const int oy  = t % H_;
    const int oz  = t / H_;

    f4 A0, A1, A2, A3, A4, A5, A6;
#define INIT4(Ai, kb) { f4 v; \
    v.x = offb[((kb) + 0) * 3 + d]; \
    v.y = offb[((kb) + 1) * 3 + d]; \
    v.z = offb[((kb) + 2) * 3 + d]; \
    v.w = ((kb) + 3 < KPTS) ? offb[((kb) + 3) * 3 + d] : 0.0f; \
    Ai = v; }
    INIT4(A0, 0) INIT4(A1, 4) INIT4(A2, 8) INIT4(A3, 12)
    INIT4(A4, 16) INIT4(A5, 20) INIT4(A6, 24)
#undef INIT4

    for (int tap = 0; tap < KPTS; ++tap) {
        const int kz = tap / 9, ky = (tap / 3) % 3, kx = tap % 3;
        const int zi = oz - 1 + kz, yi = oy - 1 + ky, xi = ox - 1 + kx;
        const bool val = ((unsigned)zi < (unsigned)D_) &&
                         ((unsigned)yi < (unsigned)H_) &&
                         ((unsigned)xi < (unsigned)W_);
        const int zc = iclamp(zi, 0, D_ - 1);
        const int yc = iclamp(yi, 0, H_ - 1);
        const int xc = iclamp(xi, 0, W_ - 1);
        const float m = val ? 1.0f : 0.0f;
        const f4* src = (const f4*)(xT + (size_t)((zc * H_ + yc) * W_ + xc) * CIN);

        f4 X0 = src[0] * m, X1 = src[1] * m, X2 = src[2] * m, X3 = src[3] * m;
        f4 X4 = src[4] * m, X5 = src[5] * m, X6 = src[6] * m, X7 = src[7] * m;

        // uniform weight slice for (tap, d): [c][28]; 7 f4 per channel
        const f4* w4 = (const f4*)(owT + (size_t)((tap * 3 + d) * CIN) * KPAD);
#define OF(xs, cfull) { const float s_ = (xs); const f4* wp = w4 + (cfull) * 7; \
    A0 += wp[0] * s_; A1 += wp[1] * s_; A2 += wp[2] * s_; A3 += wp[3] * s_; \
    A4 += wp[4] * s_; A5 += wp[5] * s_; A6 += wp[6] * s_; }
#define OCC(Xi, cc) { OF(Xi.x, (cc)*4+0) OF(Xi.y, (cc)*4+1) \
                      OF(Xi.z, (cc)*4+2) OF(Xi.w, (cc)*4+3) }
        OCC(X0, 0) OCC(X1, 1) OCC(X2, 2) OCC(X3, 3)
        OCC(X4, 4) OCC(X5, 5) OCC(X6, 6) OCC(X7, 7)
#undef OCC
#undef OF
    }

    // coords[d][kpt][p] = offset + base-grid component
#define BASEF(kk) ((d == 0) ? (float)(oz - 1 + (kk) / 9) \
                 : (d == 1) ? (float)(oy - 1 + ((kk) / 3) % 3) \
                            : (float)(ox - 1 + (kk) % 3))
#define WOUT(Ai, kb) { \
    coords[(d * KPTS + (kb) + 0) * NP + p] = Ai.x + BASEF((kb) + 0); \
    coords[(d * KPTS + (kb) + 1) * NP + p] = Ai.y + BASEF((kb) + 1); \
    coords[(d * KPTS + (kb) + 2) * NP + p] = Ai.z + BASEF((kb) + 2); \
    if ((kb) + 3 < KPTS) \
        coords[(d * KPTS + (kb) + 3) * NP + p] = Ai.w + BASEF((kb) + 3); }
    WOUT(A0, 0) WOUT(A1, 4) WOUT(A2, 8) WOUT(A3, 12)
    WOUT(A4, 16) WOUT(A5, 20) WOUT(A6, 24)
#undef WOUT
#undef BASEF
}

// ---------------------------------------------------------------------------
// Kernel B: fused trilinear sampling + contraction. blockIdx.y = tap group
// (9 taps). 64 out-channels in NAMED f4 registers A0..A15. Weights read
// directly from the uniform wT pointer (-> s_load, SMEM pipe, zero LDS).
// ---------------------------------------------------------------------------
__global__ __launch_bounds__(64, 2) void k_dconv(const float* __restrict__ xT,
                                                 const float* __restrict__ coords,
                                                 const float* __restrict__ wT,
                                                 float* __restrict__ out) {
    const int tid = threadIdx.x;
    const int p   = blockIdx.x * 64 + tid;
    const int g   = blockIdx.y;                      // 0..2, taps [9g, 9g+9)

    f4 A0 = 0, A1 = 0, A2 = 0, A3 = 0, A4 = 0, A5 = 0, A6 = 0, A7 = 0;
    f4 A8 = 0, A9 = 0, A10 = 0, A11 = 0, A12 = 0, A13 = 0, A14 = 0, A15 = 0;

    for (int tap = 9 * g; tap < 9 * g + 9; ++tap) {
        const float cz = coords[(0 * KPTS + tap) * NP + p];
        const float cy = coords[(1 * KPTS + tap) * NP + p];
        const float cx = coords[(2 * KPTS + tap) * NP + p];

        const float zf = floorf(cz), yf = floorf(cy), xf = floorf(cx);
        const float fz = cz - zf, fy = cy - yf, fx = cx - xf;
        const int z0 = (int)zf, y0 = (int)yf, x0 = (int)xf;

        float cw0, cw1, cw2, cw3, cw4, cw5, cw6, cw7;
        int   cb0, cb1, cb2, cb3, cb4, cb5, cb6, cb7;
#define CORNER(jj, Wj, Bj) { \
    const int dz_ = (jj) >> 2, dy_ = ((jj) >> 1) & 1, dx_ = (jj) & 1; \
    const int zi_ = z0 + dz_, yi_ = y0 + dy_, xi_ = x0 + dx_; \
    const bool v_ = ((unsigned)zi_ < (unsigned)D_) && \
                    ((unsigned)yi_ < (unsigned)H_) && \
                    ((unsigned)xi_ < (unsigned)W_); \
    const float wz_ = dz_ ? fz : 1.0f - fz; \
    const float wy_ = dy_ ? fy : 1.0f - fy; \
    const float wx_ = dx_ ? fx : 1.0f - fx; \
    Wj = v_ ? wz_ * wy_ * wx_ : 0.0f; \
    Bj = ((iclamp(zi_, 0, D_ - 1) * H_ + iclamp(yi_, 0, H_ - 1)) * W_ \
          + iclamp(xi_, 0, W_ - 1)) * CIN; }
        CORNER(0, cw0, cb0) CORNER(1, cw1, cb1) CORNER(2, cw2, cb2)
        CORNER(3, cw3, cb3) CORNER(4, cw4, cb4) CORNER(5, cw5, cb5)
        CORNER(6, cw6, cb6) CORNER(7, cw7, cb7)
#undef CORNER

        // uniform weight slice for tap: [c][o], 16 f4 per (c)
        const f4* w4 = (const f4*)(wT + (size_t)tap * CIN * COUT);
#define LDX(Bj, cc) (*(const f4*)(xT + (Bj) + (cc) * 4))
#define SFMA(sv, eidx, cc) { const float s_ = (sv); \
    const f4* wq = w4 + (((cc) * 4 + (eidx)) * 16); \
    A0  += wq[0]  * s_; A1  += wq[1]  * s_; A2  += wq[2]  * s_; A3  += wq[3]  * s_; \
    A4  += wq[4]  * s_; A5  += wq[5]  * s_; A6  += wq[6]  * s_; A7  += wq[7]  * s_; \
    A8  += wq[8]  * s_; A9  += wq[9]  * s_; A10 += wq[10] * s_; A11 += wq[11] * s_; \
    A12 += wq[12] * s_; A13 += wq[13] * s_; A14 += wq[14] * s_; A15 += wq[15] * s_; }
#define CCBLK(cc) { \
    f4 s = cw0 * LDX(cb0, cc); \
    s += cw1 * LDX(cb1, cc);  s += cw2 * LDX(cb2, cc); \
    s += cw3 * LDX(cb3, cc);  s += cw4 * LDX(cb4, cc); \
    s += cw5 * LDX(cb5, cc);  s += cw6 * LDX(cb6, cc); \
    s += cw7 * LDX(cb7, cc); \
    SFMA(s.x, 0, cc) SFMA(s.y, 1, cc) SFMA(s.z, 2, cc) SFMA(s.w, 3, cc) }
        CCBLK(0) CCBLK(1) CCBLK(2) CCBLK(3)
        CCBLK(4) CCBLK(5) CCBLK(6) CCBLK(7)
#undef CCBLK
#undef SFMA
#undef LDX
    }

    float* op = out + p;
#define AOUT(Ai, ob) { \
    atomicAdd(op + ((ob) + 0) * NP, Ai.x); atomicAdd(op + ((ob) + 1) * NP, Ai.y); \
    atomicAdd(op + ((ob) + 2) * NP, Ai.z); atomicAdd(op + ((ob) + 3) * NP, Ai.w); }
    AOUT(A0, 0)  AOUT(A1, 4)  AOUT(A2, 8)   AOUT(A3, 12)
    AOUT(A4, 16) AOUT(A5, 20) AOUT(A6, 24)  AOUT(A7, 28)
    AOUT(A8, 32) AOUT(A9, 36) AOUT(A10, 40) AOUT(A11, 44)
    AOUT(A12, 48) AOUT(A13, 52) AOUT(A14, 56) AOUT(A15, 60)
#undef AOUT
}

// ---------------------------------------------------------------------------
extern "C" void kernel_launch(void* const* d_in, const int* in_sizes, int n_in,
                              void* d_out, int out_size, void* d_ws, size_t ws_size,
                              hipStream_t stream) {
    const float* x    = (const float*)d_in[0];  // [32,16,56,56]
    const float* offw = (const float*)d_in[1];  // [81,32,3,3,3]
    const float* offb = (const float*)d_in[2];  // [81]
    const float* wgt  = (const float*)d_in[3];  // [64,32,3,3,3]
    const float* bias = (const float*)d_in[4];  // [64]
    float* out = (float*)d_out;                 // [64,16,56,56]

    float* ws     = (float*)d_ws;
    float* coords = ws;                            // 3*27*NP       (~16.3 MB)
    float* wT     = coords + 3 * KPTS * NP;        // 27*32*64
    float* owT    = wT + KPTS * CIN * COUT;        // 27*3*32*28
    float* xT     = owT + KPTS * 3 * CIN * KPAD;   // NP*32         (~6.4 MB)

    const int n_tr = NCH * CIN * KPTS;             // 69984
    hipLaunchKernelGGL(k_prep, dim3((n_tr + 255) / 256), dim3(256), 0, stream,
                       wgt, offw, wT, owT);
    hipLaunchKernelGGL(k_xT, dim3(NP / 64), dim3(64), 0, stream, x, xT);
    hipLaunchKernelGGL(k_init, dim3(COUT * NP / 4 / 256), dim3(256), 0, stream,
                       bias, out);
    hipLaunchKernelGGL(k_offsets, dim3(NP / 64, 3), dim3(64), 0, stream,
                       xT, owT, offb, coords);
    hipLaunchKernelGGL(k_dconv, dim3(NP / 64, 3), dim3(64), 0, stream,
                       xT, coords, wT, out);
}